// Round 7
// baseline (161.370 us; speedup 1.0000x reference)
//
#include <hip/hip_runtime.h>

// GCN layer:
//   g   = bf16( feat @ W^T )                    (bf16 MFMA GEMM)
//   out = (sw+1)*g + b + sum_{e:dst=d}(w_e+1)*g[src_e]
// Pipeline (3 dispatches):
//   memset(gcur)
//   fused: blocks [0,GB)   = MFMA GEMM -> g  (feat tile in LDS, W B-fragments
//          loaded straight from global f32 + converted — W is L2-resident;
//          no W LDS tile -> 17.4 KB LDS, high occupancy)
//          blocks [GB,+SB) = coarse bucket scatter (32 nodes/bucket)
//   bucket_gather: 2 blocks per bucket (16 nodes each); LDS fine sort of its
//          half; register gather; self-term + bias; pure stores to out.
// NOTE: packs src (<65536) and dst&31 into one u32 — requires N <= 65536.

#define F 128
#define NPB 32          // nodes per bucket (scatter granularity)
#define CAPB 1408       // bucket capacity (mean 512 @ E=800k,N=50k)
#define CAPH 896        // per-half-bucket LDS capacity (mean 256)
#define CHUNK 4096      // edges per scatter block
#define MAXNB 1600      // hist sizing (N <= 51200)

typedef __attribute__((ext_vector_type(8))) short short8;
typedef __attribute__((ext_vector_type(4))) float f32x4;

__device__ inline unsigned short f2b(float f) {           // f32 -> bf16 RNE
    union { float f; unsigned u; } v; v.f = f;
    unsigned r = (v.u + 0x7fffu + ((v.u >> 16) & 1u)) >> 16;
    return (unsigned short)r;
}
__device__ inline float blo(unsigned u) { union { unsigned u; float f; } x; x.u = u << 16; return x.f; }
__device__ inline float bhi(unsigned u) { union { unsigned u; float f; } x; x.u = u & 0xffff0000u; return x.f; }

struct __align__(8) Edge { unsigned pk; float w; };  // pk = src | (dst_local<<16)

// ---------------- Fused: GEMM (blocks < GB) + bucket scatter (rest) ---------
__global__ __launch_bounds__(256) void gemm_scatter(
    const float* __restrict__ feat, const float* __restrict__ W,
    const int* __restrict__ dst, const int* __restrict__ src,
    const float* __restrict__ weight,
    unsigned short* __restrict__ g, int* __restrict__ gcur,
    Edge* __restrict__ sorted, int M, int E, int GB, int NB)
{
    __shared__ __align__(16) char smem[64 * 136 * 2];   // 17408 B
    const int tid = threadIdx.x;

    if ((int)blockIdx.x < GB) {
        // ---------------- GEMM part ----------------
        unsigned short* ftl = (unsigned short*)smem;    // [64][136] bf16
        const int row0 = blockIdx.x * 64;

        for (int i = tid; i < 64 * 32; i += 256) {      // feat tile f32->bf16
            int r = i >> 5, c4 = i & 31;
            int rr = row0 + r; if (rr >= M) rr = M - 1;
            float4 v = ((const float4*)feat)[(size_t)rr * 32 + c4];
            ushort4 h; h.x = f2b(v.x); h.y = f2b(v.y); h.z = f2b(v.z); h.w = f2b(v.w);
            *(ushort4*)&ftl[r * 136 + c4 * 4] = h;
        }
        __syncthreads();

        const int lane = tid & 63, wid = tid >> 6;
        const int m = lane & 15, quad = lane >> 4;
        const int rbase = wid * 16;

        f32x4 acc[8];
#pragma unroll
        for (int t = 0; t < 8; ++t) acc[t] = (f32x4){0.f, 0.f, 0.f, 0.f};

#pragma unroll
        for (int kk = 0; kk < 4; ++kk) {
            const int k0 = kk * 32 + quad * 8;
            short8 a = *(const short8*)&ftl[(rbase + m) * 136 + k0];
#pragma unroll
            for (int t = 0; t < 8; ++t) {
                // B-fragment straight from global W (f32, L2-hot): row t*16+m,
                // cols k0..k0+7. Per instr: 16 rows x 64 B, fully used.
                const float4 w0 = *(const float4*)&W[(size_t)(t * 16 + m) * F + k0];
                const float4 w1 = *(const float4*)&W[(size_t)(t * 16 + m) * F + k0 + 4];
                short8 bf;
                bf[0] = (short)f2b(w0.x); bf[1] = (short)f2b(w0.y);
                bf[2] = (short)f2b(w0.z); bf[3] = (short)f2b(w0.w);
                bf[4] = (short)f2b(w1.x); bf[5] = (short)f2b(w1.y);
                bf[6] = (short)f2b(w1.z); bf[7] = (short)f2b(w1.w);
                acc[t] = __builtin_amdgcn_mfma_f32_16x16x32_bf16(a, bf, acc[t], 0, 0, 0);
            }
        }

#pragma unroll
        for (int reg = 0; reg < 4; ++reg) {
            int r = row0 + rbase + quad * 4 + reg;
            if (r < M) {
#pragma unroll
                for (int t = 0; t < 8; ++t)
                    g[(size_t)r * F + t * 16 + m] = f2b(acc[t][reg]);
            }
        }
    } else {
        // ---------------- Scatter part ----------------
        int* hist  = (int*)smem;            // [MAXNB]  (12.8 KB used)
        int* lbase = hist + MAXNB;
        const int e0 = ((int)blockIdx.x - GB) * CHUNK;

        for (int i = tid; i < NB; i += 256) hist[i] = 0;
        __syncthreads();
#pragma unroll
        for (int j = 0; j < CHUNK / 256; ++j) {
            int e = e0 + j * 256 + tid;
            if (e < E) atomicAdd(&hist[dst[e] >> 5], 1);
        }
        __syncthreads();
        for (int i = tid; i < NB; i += 256) {
            int c = hist[i];
            lbase[i] = c ? atomicAdd(&gcur[i], c) : 0;
            hist[i] = 0;
        }
        __syncthreads();
#pragma unroll
        for (int j = 0; j < CHUNK / 256; ++j) {
            int e = e0 + j * 256 + tid;
            if (e < E) {
                int d = dst[e];
                int bkt = d >> 5;
                int pos = lbase[bkt] + atomicAdd(&hist[bkt], 1);
                if (pos < CAPB) {
                    Edge ed;
                    ed.pk = (unsigned)src[e] | ((unsigned)(d & 31) << 16);
                    ed.w = weight[e] + 1.0f;
                    sorted[(size_t)bkt * CAPB + pos] = ed;
                }
            }
        }
    }
}

// ------- Per-HALF-bucket fine sort + register gather + epilogue -------------
// 2 blocks per bucket; each handles 16 nodes. Small LDS -> high occupancy.
__global__ __launch_bounds__(256) void bucket_gather(
    const unsigned short* __restrict__ g, const Edge* __restrict__ sorted,
    const int* __restrict__ gcur, const float* __restrict__ sw,
    const float* __restrict__ bvec, float* __restrict__ out, int M)
{
    __shared__ Edge ebuf[CAPH];                 // 7 KB
    __shared__ int hcnt[16];
    __shared__ int off[17];
    __shared__ int cur[16];

    const int tid = threadIdx.x;
    const int b = blockIdx.x >> 1, half = blockIdx.x & 1;
    int cnt = gcur[b]; if (cnt > CAPB) cnt = CAPB;
    const Edge* sb = sorted + (size_t)b * CAPB;

    if (tid < 16) hcnt[tid] = 0;
    __syncthreads();

    // Pass 1: histogram of this half's 16 nodes.
    for (int i = tid; i < cnt; i += 256) {
        int dl = sb[i].pk >> 16;
        if ((dl >> 4) == half) atomicAdd(&hcnt[dl & 15], 1);
    }
    __syncthreads();
    if (tid < 16) {                             // 16-entry scan in wave 0
        int v = hcnt[tid];
        int x = v;
#pragma unroll
        for (int s = 1; s < 16; s <<= 1) {
            int t = __shfl_up(x, s, 64);
            if (tid >= s) x += t;
        }
        off[tid + 1] = x;
        if (tid == 0) off[0] = 0;
        cur[tid] = x - v;
    }
    __syncthreads();
    // Pass 2: place this half's edges node-sorted into LDS (sorted re-read
    // hits L2/L1 — cheap, avoids register-array spill).
    for (int i = tid; i < cnt; i += 256) {
        Edge e = sb[i];
        int dl = e.pk >> 16;
        if ((dl >> 4) == half) {
            int p = atomicAdd(&cur[dl & 15], 1);
            if (p < CAPH) ebuf[p] = e;
        }
    }
    __syncthreads();

    // Gather: 16 lane-groups of 16 lanes; one node per group.
    const int grp = tid >> 4, c = tid & 15;
    const int node = b * NPB + half * 16 + grp;
    if (node >= M) return;
    int p = off[grp];
    int pe = off[grp + 1]; if (pe > CAPH) pe = CAPH;

    const float4 b0 = ((const float4*)bvec)[c * 2];
    const float4 b1 = ((const float4*)bvec)[c * 2 + 1];

    float acc[8] = {0.f, 0.f, 0.f, 0.f, 0.f, 0.f, 0.f, 0.f};
    for (; p + 1 < pe; p += 2) {                // 2 outstanding g-row loads
        Edge e0 = ebuf[p], e1 = ebuf[p + 1];
        const uint4 r0 = *(const uint4*)(g + (size_t)(e0.pk & 0xffffu) * F + c * 8);
        const uint4 r1 = *(const uint4*)(g + (size_t)(e1.pk & 0xffffu) * F + c * 8);
        float w0 = e0.w, w1 = e1.w;
        acc[0] = fmaf(w0, blo(r0.x), acc[0]); acc[1] = fmaf(w0, bhi(r0.x), acc[1]);
        acc[2] = fmaf(w0, blo(r0.y), acc[2]); acc[3] = fmaf(w0, bhi(r0.y), acc[3]);
        acc[4] = fmaf(w0, blo(r0.z), acc[4]); acc[5] = fmaf(w0, bhi(r0.z), acc[5]);
        acc[6] = fmaf(w0, blo(r0.w), acc[6]); acc[7] = fmaf(w0, bhi(r0.w), acc[7]);
        acc[0] = fmaf(w1, blo(r1.x), acc[0]); acc[1] = fmaf(w1, bhi(r1.x), acc[1]);
        acc[2] = fmaf(w1, blo(r1.y), acc[2]); acc[3] = fmaf(w1, bhi(r1.y), acc[3]);
        acc[4] = fmaf(w1, blo(r1.z), acc[4]); acc[5] = fmaf(w1, bhi(r1.z), acc[5]);
        acc[6] = fmaf(w1, blo(r1.w), acc[6]); acc[7] = fmaf(w1, bhi(r1.w), acc[7]);
    }
    if (p < pe) {
        Edge e0 = ebuf[p];
        const uint4 r0 = *(const uint4*)(g + (size_t)(e0.pk & 0xffffu) * F + c * 8);
        float w0 = e0.w;
        acc[0] = fmaf(w0, blo(r0.x), acc[0]); acc[1] = fmaf(w0, bhi(r0.x), acc[1]);
        acc[2] = fmaf(w0, blo(r0.y), acc[2]); acc[3] = fmaf(w0, bhi(r0.y), acc[3]);
        acc[4] = fmaf(w0, blo(r0.z), acc[4]); acc[5] = fmaf(w0, bhi(r0.z), acc[5]);
        acc[6] = fmaf(w0, blo(r0.w), acc[6]); acc[7] = fmaf(w0, bhi(r0.w), acc[7]);
    }

    // Self-term + bias epilogue (pure stores; out never read).
    const uint4 sr = *(const uint4*)(g + (size_t)node * F + c * 8);
    const float s = sw[node] + 1.0f;
    float4 o0, o1;
    o0.x = fmaf(s, blo(sr.x), b0.x) + acc[0];
    o0.y = fmaf(s, bhi(sr.x), b0.y) + acc[1];
    o0.z = fmaf(s, blo(sr.y), b0.z) + acc[2];
    o0.w = fmaf(s, bhi(sr.y), b0.w) + acc[3];
    o1.x = fmaf(s, blo(sr.z), b1.x) + acc[4];
    o1.y = fmaf(s, bhi(sr.z), b1.y) + acc[5];
    o1.z = fmaf(s, blo(sr.w), b1.z) + acc[6];
    o1.w = fmaf(s, bhi(sr.w), b1.w) + acc[7];
    float4* o = (float4*)(out + (size_t)node * F + c * 8);
    o[0] = o0; o[1] = o1;
}

extern "C" void kernel_launch(void* const* d_in, const int* in_sizes, int n_in,
                              void* d_out, int out_size, void* d_ws, size_t ws_size,
                              hipStream_t stream) {
    const float* feat   = (const float*)d_in[0];
    const float* sw     = (const float*)d_in[1];
    const float* weight = (const float*)d_in[2];
    const int*   src    = (const int*)  d_in[3];
    const int*   dst    = (const int*)  d_in[4];
    const float* W      = (const float*)d_in[5];
    const float* b      = (const float*)d_in[6];
    float* out = (float*)d_out;

    const int M = in_sizes[1];   // N
    const int E = in_sizes[2];
    const int NB = (M + NPB - 1) / NPB;
    const int GB = (M + 63) / 64;
    const int SB = (E + CHUNK - 1) / CHUNK;

    // Workspace layout (256 B aligned)
    char* ws = (char*)d_ws;
    size_t og    = 0;                                                  // g bf16
    size_t ocur  = ((og   + (size_t)M * F * 2) + 255) & ~(size_t)255;  // gcur[NB]
    size_t osort = ((ocur + (size_t)NB * 4) + 255) & ~(size_t)255;     // Edge[NB*CAPB]

    unsigned short* g = (unsigned short*)(ws + og);
    int*  gcur   = (int*)(ws + ocur);
    Edge* sorted = (Edge*)(ws + osort);

    hipMemsetAsync(gcur, 0, (size_t)NB * 4, stream);
    gemm_scatter<<<GB + SB, 256, 0, stream>>>(
        feat, W, dst, src, weight, g, gcur, sorted, M, E, GB, NB);
    bucket_gather<<<NB * 2, 256, 0, stream>>>(g, sorted, gcur, sw, b, out, M);
}